// Round 1
// baseline (288.312 us; speedup 1.0000x reference)
//
#include <hip/hip_runtime.h>
#include <hip/hip_bf16.h>
#include <math.h>

#define BSZ 4
#define NN 512
#define DD 64
#define NKEEP 256

// ---------------- Kernel 1: scores + softmax + agg, one block per (b,i) row ----
__global__ __launch_bounds__(256) void k_att(
    const float* __restrict__ x, const float* __restrict__ apw,
    const float* __restrict__ apb, const float* __restrict__ aw,
    float* __restrict__ agg) {
  __shared__ float sp[32 * 256];     // p = xi*xj, transposed [d][tid], 32 KB
  __shared__ float sxi[DD];
  __shared__ float ssc[NN];          // att weights after softmax
  __shared__ float sred[8];
  __shared__ float sagg[4][DD];

  const int t = threadIdx.x;
  const int b = blockIdx.x >> 9;
  const int i = blockIdx.x & (NN - 1);
  const float* xb = x + (size_t)b * NN * DD;

  if (t < DD) sxi[t] = xb[(size_t)i * DD + t];
  __syncthreads();

  float sc[2];
  #pragma unroll
  for (int pass = 0; pass < 2; ++pass) {
    const int j = t + pass * 256;
    const float* xj = xb + (size_t)j * DD;
    float acc[DD];
    #pragma unroll
    for (int e = 0; e < DD; ++e) acc[e] = apb[e];

    #pragma unroll
    for (int half = 0; half < 2; ++half) {
      // stage p[d] = xi[d]*xj[d] for d in [half*32, half*32+32) into own LDS column
      #pragma unroll
      for (int q = 0; q < 8; ++q) {
        const int d0 = half * 32 + q * 4;
        float4 v = *reinterpret_cast<const float4*>(xj + d0);
        sp[(q * 4 + 0) * 256 + t] = v.x * sxi[d0 + 0];
        sp[(q * 4 + 1) * 256 + t] = v.y * sxi[d0 + 1];
        sp[(q * 4 + 2) * 256 + t] = v.z * sxi[d0 + 2];
        sp[(q * 4 + 3) * 256 + t] = v.w * sxi[d0 + 3];
      }
      // no barrier: each thread reads only its own column
      #pragma unroll 2
      for (int dd = 0; dd < 32; ++dd) {
        const float pd = sp[dd * 256 + t];
        const float* wr = apw + (half * 32 + dd) * DD;  // wave-uniform -> s_load
        #pragma unroll
        for (int e = 0; e < DD; ++e) acc[e] = fmaf(pd, wr[e], acc[e]);
      }
    }
    float sdot = 0.f;
    #pragma unroll
    for (int e = 0; e < DD; ++e) sdot = fmaf(aw[e], tanhf(acc[e]), sdot);
    sc[pass] = sdot;
  }

  // ---- softmax over j (512 values: sc[0] at j=t, sc[1] at j=t+256) ----
  const int w = t >> 6, lane = t & 63;
  float m = fmaxf(sc[0], sc[1]);
  #pragma unroll
  for (int off = 32; off; off >>= 1) m = fmaxf(m, __shfl_xor(m, off, 64));
  if (lane == 0) sred[w] = m;
  __syncthreads();
  m = fmaxf(fmaxf(sred[0], sred[1]), fmaxf(sred[2], sred[3]));

  float e0 = expf(sc[0] - m), e1 = expf(sc[1] - m);
  float ps = e0 + e1;
  #pragma unroll
  for (int off = 32; off; off >>= 1) ps += __shfl_xor(ps, off, 64);
  if (lane == 0) sred[4 + w] = ps;
  __syncthreads();
  const float S = sred[4] + sred[5] + sred[6] + sred[7];
  const float inv = 1.f / S;
  ssc[t] = e0 * inv;
  ssc[t + 256] = e1 * inv;
  __syncthreads();

  // ---- agg[b,i,d] = sum_j att[j] * x[b,j,d] ----
  const int c = t >> 6, d = t & 63;
  float part = 0.f;
  for (int q = 0; q < 128; ++q) {
    const int j = c * 128 + q;
    part = fmaf(ssc[j], xb[(size_t)j * DD + d], part);
  }
  sagg[c][d] = part;
  __syncthreads();
  if (t < DD) {
    agg[((size_t)b * NN + i) * DD + t] =
        sagg[0][t] + sagg[1][t] + sagg[2][t] + sagg[3][t];
  }
}

// ---------------- Kernel 2: h = agg@pwa + x@pwoa + biases; BN; SELU; s ----------
__global__ __launch_bounds__(256) void k_h(
    const float* __restrict__ x, const float* __restrict__ agg,
    const float* __restrict__ pwa, const float* __restrict__ pwab,
    const float* __restrict__ pwoa, const float* __restrict__ pwob,
    const float* __restrict__ gam, const float* __restrict__ bet,
    const float* __restrict__ mu, const float* __restrict__ var,
    const float* __restrict__ poolw, const float* __restrict__ poolb,
    float* __restrict__ h, float* __restrict__ s) {
  const int t = threadIdx.x;
  const int w = t >> 6, e = t & 63;
  const int row = blockIdx.x * 4 + w;  // 0..2047
  const float* xr = x + (size_t)row * DD;
  const float* ar = agg + (size_t)row * DD;

  float acc = pwab[e] + pwob[e];
  #pragma unroll 4
  for (int d = 0; d < DD; ++d) {
    acc = fmaf(ar[d], pwa[d * DD + e], acc);
    acc = fmaf(xr[d], pwoa[d * DD + e], acc);
  }
  // BatchNorm (eval, running stats)
  float hb = (acc - mu[e]) * rsqrtf(var[e] + 1e-5f) * gam[e] + bet[e];
  // SELU
  const float SC = 1.0507009873554805f, AL = 1.6732632423543772f;
  float hv = hb > 0.f ? SC * hb : SC * AL * expm1f(hb);
  h[(size_t)row * DD + e] = hv;

  float p = hv * poolw[e];
  #pragma unroll
  for (int off = 32; off; off >>= 1) p += __shfl_xor(p, off, 64);
  if (e == 0) s[row] = 1.f / (1.f + expf(-(p + poolb[0])));
}

// ---------------- Kernel 3: per-batch top-k (bitonic sort) + gather -------------
__global__ __launch_bounds__(256) void k_topk(
    const float* __restrict__ s, const float* __restrict__ h,
    float* __restrict__ out) {
  __shared__ float sv[NN];
  __shared__ int si[NN];
  const int b = blockIdx.x, t = threadIdx.x;
  sv[t] = s[b * NN + t];
  sv[t + 256] = s[b * NN + t + 256];
  si[t] = t;
  si[t + 256] = t + 256;
  __syncthreads();

  // sort descending by value, ties ascending index (matches jax.lax.top_k)
  for (int k = 2; k <= NN; k <<= 1) {
    for (int j = k >> 1; j > 0; j >>= 1) {
      #pragma unroll
      for (int base = 0; base < 2; ++base) {
        const int a = t + base * 256;
        const int p2 = a ^ j;
        if (p2 > a) {
          float va = sv[a], vb = sv[p2];
          int ia = si[a], ib = si[p2];
          const bool aFirst = (va > vb) || (va == vb && ia < ib);
          const bool desc = ((a & k) == 0);
          if (desc ? !aFirst : aFirst) {
            sv[a] = vb; sv[p2] = va;
            si[a] = ib; si[p2] = ia;
          }
        }
      }
      __syncthreads();
    }
  }

  // out[b,kk,:] = h[b, idx[kk], :] * s_sorted[kk]
  for (int pos = t; pos < NKEEP * DD; pos += 256) {
    const int kk = pos >> 6, d = pos & 63;
    out[((size_t)b * NKEEP + kk) * DD + d] =
        h[((size_t)b * NN + si[kk]) * DD + d] * sv[kk];
  }
}

extern "C" void kernel_launch(void* const* d_in, const int* in_sizes, int n_in,
                              void* d_out, int out_size, void* d_ws, size_t ws_size,
                              hipStream_t stream) {
  const float* x     = (const float*)d_in[0];
  const float* apw   = (const float*)d_in[1];
  const float* apb   = (const float*)d_in[2];
  const float* aw    = (const float*)d_in[3];
  const float* pwa   = (const float*)d_in[4];
  const float* pwab  = (const float*)d_in[5];
  const float* pwoa  = (const float*)d_in[6];
  const float* pwob  = (const float*)d_in[7];
  const float* gam   = (const float*)d_in[8];
  const float* bet   = (const float*)d_in[9];
  const float* mu    = (const float*)d_in[10];
  const float* var   = (const float*)d_in[11];
  const float* poolw = (const float*)d_in[12];
  const float* poolb = (const float*)d_in[13];
  float* out = (float*)d_out;

  float* agg = (float*)d_ws;                 // BSZ*NN*DD floats
  float* h   = agg + (size_t)BSZ * NN * DD;  // BSZ*NN*DD floats
  float* s   = h + (size_t)BSZ * NN * DD;    // BSZ*NN floats

  k_att<<<BSZ * NN, 256, 0, stream>>>(x, apw, apb, aw, agg);
  k_h<<<BSZ * NN / 4, 256, 0, stream>>>(x, agg, pwa, pwab, pwoa, pwob,
                                        gam, bet, mu, var, poolw, poolb, h, s);
  k_topk<<<BSZ, 256, 0, stream>>>(s, h, out);
}

// Round 2
// 110.868 us; speedup vs baseline: 2.6005x; 2.6005x over previous
//
#include <hip/hip_runtime.h>
#include <hip/hip_bf16.h>
#include <math.h>

#define BSZ 4
#define NN 512
#define DD 64
#define NKEEP 256

typedef __attribute__((ext_vector_type(8))) short short8;
typedef __attribute__((ext_vector_type(4))) float f32x4;

__device__ __forceinline__ ushort f2bf_rne(float f) {
  union { float f; unsigned u; } v; v.f = f;
  unsigned r = v.u + 0x7fffu + ((v.u >> 16) & 1u);
  return (ushort)(r >> 16);
}
__device__ __forceinline__ float bf2f(ushort h) {
  union { unsigned u; float f; } v; v.u = ((unsigned)h) << 16;
  return v.f;
}
__device__ __forceinline__ float fast_tanh(float x) {
  // tanh(x) = 1 - 2/(exp(2x)+1), via v_exp_f32 (2^t) + v_rcp_f32
  float e = __builtin_amdgcn_exp2f(x * 2.8853900817779268f);
  float r = __builtin_amdgcn_rcpf(e + 1.0f);
  return 1.0f - 2.0f * r;
}

// ---- prep: split att_proj_w (64x64, [d][e]) into hi/lo bf16, transposed [e][d]
__global__ void k_prep(const float* __restrict__ apw,
                       ushort* __restrict__ wht, ushort* __restrict__ wlt) {
  const int idx = blockIdx.x * 256 + threadIdx.x;  // 0..4095
  const int d = idx >> 6, e = idx & 63;
  const float wv = apw[idx];
  const ushort h = f2bf_rne(wv);
  const ushort lo = f2bf_rne(wv - bf2f(h));
  wht[e * 64 + d] = h;
  wlt[e * 64 + d] = lo;
}

// ---- fused attention row kernel: one block per (b,i) ----
__global__ __launch_bounds__(256) void k_att2(
    const float* __restrict__ x, const ushort* __restrict__ wht,
    const ushort* __restrict__ wlt, const float* __restrict__ apb,
    const float* __restrict__ aw, float* __restrict__ agg) {
  __shared__ ushort Ph[128 * 64];  // 16 KB, XOR-swizzled
  __shared__ ushort Pl[128 * 64];  // 16 KB
  __shared__ float sxi[DD];
  __shared__ float ssc[NN];
  __shared__ float sred[8];
  __shared__ float sagg[4][DD];

  const int t = threadIdx.x;
  const int w = t >> 6;   // wave 0..3
  const int l = t & 63;   // lane
  const int b = blockIdx.x >> 9;
  const int i = blockIdx.x & (NN - 1);
  const float* xb = x + (size_t)b * NN * DD;

  if (t < DD) sxi[t] = xb[(size_t)i * DD + t];

  // preload W fragments into registers: wf[eq][ks], B-operand of 16x16x32
  // B elem (k=d, col=e): lane holds e=l&15, d = ks*32 + (l>>4)*8 + 0..7
  short8 wfh[4][2], wfl[4][2];
  {
    const int e = l & 15, g = l >> 4;
    #pragma unroll
    for (int eq = 0; eq < 4; ++eq)
      #pragma unroll
      for (int ks = 0; ks < 2; ++ks) {
        const int off = (eq * 16 + e) * 64 + ks * 32 + g * 8;
        wfh[eq][ks] = *reinterpret_cast<const short8*>(wht + off);
        wfl[eq][ks] = *reinterpret_cast<const short8*>(wlt + off);
      }
  }
  float aw4[4], ab4[4];
  {
    const int e0 = l & 15;
    #pragma unroll
    for (int eq = 0; eq < 4; ++eq) {
      aw4[eq] = aw[eq * 16 + e0];
      ab4[eq] = apb[eq * 16 + e0];
    }
  }
  __syncthreads();

  const int jl_w = t >> 1;         // 0..127: P-build row
  const int dh = (t & 1) * 32;     // d half

  #pragma unroll 1
  for (int c = 0; c < 4; ++c) {
    // ---- build P chunk (128 j x 64 d), split into hi/lo bf16, swizzled ----
    const float* xj = xb + (size_t)(c * 128 + jl_w) * DD + dh;
    #pragma unroll
    for (int q = 0; q < 8; ++q) {
      float4 v = *reinterpret_cast<const float4*>(xj + q * 4);
      float4 xi = *reinterpret_cast<const float4*>(&sxi[dh + q * 4]);
      float p0 = v.x * xi.x, p1 = v.y * xi.y, p2 = v.z * xi.z, p3 = v.w * xi.w;
      ushort h0 = f2bf_rne(p0), h1 = f2bf_rne(p1), h2 = f2bf_rne(p2), h3 = f2bf_rne(p3);
      ushort l0 = f2bf_rne(p0 - bf2f(h0)), l1 = f2bf_rne(p1 - bf2f(h1));
      ushort l2 = f2bf_rne(p2 - bf2f(h2)), l3 = f2bf_rne(p3 - bf2f(h3));
      uint2 hw, lw;
      hw.x = (unsigned)h0 | ((unsigned)h1 << 16);
      hw.y = (unsigned)h2 | ((unsigned)h3 << 16);
      lw.x = (unsigned)l0 | ((unsigned)l1 << 16);
      lw.y = (unsigned)l2 | ((unsigned)l3 << 16);
      const int byteoff = ((jl_w * 64 + dh + q * 4) * 2) ^ ((jl_w & 7) << 4);
      *reinterpret_cast<uint2*>(reinterpret_cast<char*>(Ph) + byteoff) = hw;
      *reinterpret_cast<uint2*>(reinterpret_cast<char*>(Pl) + byteoff) = lw;
    }
    __syncthreads();

    // ---- load A fragments: A elem (row=j, k=d): j = w*32+jq*16+(l&15) ----
    short8 ah[2][2], al[2][2];
    #pragma unroll
    for (int jq = 0; jq < 2; ++jq)
      #pragma unroll
      for (int ks = 0; ks < 2; ++ks) {
        const int jr = w * 32 + jq * 16 + (l & 15);
        const int byteoff = ((jr * 64 + ks * 32 + (l >> 4) * 8) * 2) ^ ((jr & 7) << 4);
        ah[jq][ks] = *reinterpret_cast<const short8*>(reinterpret_cast<char*>(Ph) + byteoff);
        al[jq][ks] = *reinterpret_cast<const short8*>(reinterpret_cast<char*>(Pl) + byteoff);
      }

    // ---- MFMA: acc[jq][eq] (split product: Ph*Wh + Ph*Wl + Pl*Wh) ----
    f32x4 acc[2][4];
    #pragma unroll
    for (int jq = 0; jq < 2; ++jq)
      #pragma unroll
      for (int eq = 0; eq < 4; ++eq)
        acc[jq][eq] = (f32x4){0.f, 0.f, 0.f, 0.f};
    #pragma unroll
    for (int jq = 0; jq < 2; ++jq)
      #pragma unroll
      for (int eq = 0; eq < 4; ++eq)
        #pragma unroll
        for (int ks = 0; ks < 2; ++ks) {
          acc[jq][eq] = __builtin_amdgcn_mfma_f32_16x16x32_bf16(
              ah[jq][ks], wfh[eq][ks], acc[jq][eq], 0, 0, 0);
          acc[jq][eq] = __builtin_amdgcn_mfma_f32_16x16x32_bf16(
              ah[jq][ks], wfl[eq][ks], acc[jq][eq], 0, 0, 0);
          acc[jq][eq] = __builtin_amdgcn_mfma_f32_16x16x32_bf16(
              al[jq][ks], wfh[eq][ks], acc[jq][eq], 0, 0, 0);
        }

    // ---- epilogue: score[j] = sum_e aw[e]*tanh(acc + apb[e]) ----
    // D layout: col(e) = l&15, row(j) = (l>>4)*4 + r
    #pragma unroll
    for (int jq = 0; jq < 2; ++jq) {
      #pragma unroll
      for (int r = 0; r < 4; ++r) {
        float sacc = 0.f;
        #pragma unroll
        for (int eq = 0; eq < 4; ++eq)
          sacc += aw4[eq] * fast_tanh(acc[jq][eq][r] + ab4[eq]);
        sacc += __shfl_xor(sacc, 1, 64);
        sacc += __shfl_xor(sacc, 2, 64);
        sacc += __shfl_xor(sacc, 4, 64);
        sacc += __shfl_xor(sacc, 8, 64);
        if ((l & 15) == 0)
          ssc[c * 128 + w * 32 + jq * 16 + (l >> 4) * 4 + r] = sacc;
      }
    }
    __syncthreads();  // P chunk fully consumed; ssc chunk published
  }

  // ---- softmax over 512 raw scores ----
  float sc0 = ssc[t], sc1 = ssc[t + 256];
  float m = fmaxf(sc0, sc1);
  #pragma unroll
  for (int off = 32; off; off >>= 1) m = fmaxf(m, __shfl_xor(m, off, 64));
  if (l == 0) sred[w] = m;
  __syncthreads();
  m = fmaxf(fmaxf(sred[0], sred[1]), fmaxf(sred[2], sred[3]));

  const float L2E = 1.4426950408889634f;
  float e0 = __builtin_amdgcn_exp2f((sc0 - m) * L2E);
  float e1 = __builtin_amdgcn_exp2f((sc1 - m) * L2E);
  float ps = e0 + e1;
  #pragma unroll
  for (int off = 32; off; off >>= 1) ps += __shfl_xor(ps, off, 64);
  if (l == 0) sred[4 + w] = ps;
  __syncthreads();
  const float S = sred[4] + sred[5] + sred[6] + sred[7];
  const float inv = 1.f / S;
  ssc[t] = e0 * inv;
  ssc[t + 256] = e1 * inv;
  __syncthreads();

  // ---- agg[b,i,d] = sum_j att[j] * x[b,j,d] ----
  const int c2 = t >> 6, d = t & 63;
  float part = 0.f;
  for (int q = 0; q < 128; ++q) {
    const int j = c2 * 128 + q;
    part = fmaf(ssc[j], xb[(size_t)j * DD + d], part);
  }
  sagg[c2][d] = part;
  __syncthreads();
  if (t < DD) {
    agg[((size_t)b * NN + i) * DD + t] =
        sagg[0][t] + sagg[1][t] + sagg[2][t] + sagg[3][t];
  }
}

// ---------------- Kernel 2: h = agg@pwa + x@pwoa + biases; BN; SELU; s ----------
__global__ __launch_bounds__(256) void k_h(
    const float* __restrict__ x, const float* __restrict__ agg,
    const float* __restrict__ pwa, const float* __restrict__ pwab,
    const float* __restrict__ pwoa, const float* __restrict__ pwob,
    const float* __restrict__ gam, const float* __restrict__ bet,
    const float* __restrict__ mu, const float* __restrict__ var,
    const float* __restrict__ poolw, const float* __restrict__ poolb,
    float* __restrict__ h, float* __restrict__ s) {
  const int t = threadIdx.x;
  const int w = t >> 6, e = t & 63;
  const int row = blockIdx.x * 4 + w;  // 0..2047
  const float* xr = x + (size_t)row * DD;
  const float* ar = agg + (size_t)row * DD;

  float acc = pwab[e] + pwob[e];
  #pragma unroll 4
  for (int d = 0; d < DD; ++d) {
    acc = fmaf(ar[d], pwa[d * DD + e], acc);
    acc = fmaf(xr[d], pwoa[d * DD + e], acc);
  }
  float hb = (acc - mu[e]) * rsqrtf(var[e] + 1e-5f) * gam[e] + bet[e];
  const float SC = 1.0507009873554805f, AL = 1.6732632423543772f;
  float hv = hb > 0.f ? SC * hb : SC * AL * expm1f(hb);
  h[(size_t)row * DD + e] = hv;

  float p = hv * poolw[e];
  #pragma unroll
  for (int off = 32; off; off >>= 1) p += __shfl_xor(p, off, 64);
  if (e == 0) s[row] = 1.f / (1.f + expf(-(p + poolb[0])));
}

// ---------------- Kernel 3: per-batch top-k (bitonic sort) + gather -------------
__global__ __launch_bounds__(256) void k_topk(
    const float* __restrict__ s, const float* __restrict__ h,
    float* __restrict__ out) {
  __shared__ float sv[NN];
  __shared__ int si[NN];
  const int b = blockIdx.x, t = threadIdx.x;
  sv[t] = s[b * NN + t];
  sv[t + 256] = s[b * NN + t + 256];
  si[t] = t;
  si[t + 256] = t + 256;
  __syncthreads();

  for (int k = 2; k <= NN; k <<= 1) {
    for (int j = k >> 1; j > 0; j >>= 1) {
      #pragma unroll
      for (int base = 0; base < 2; ++base) {
        const int a = t + base * 256;
        const int p2 = a ^ j;
        if (p2 > a) {
          float va = sv[a], vb = sv[p2];
          int ia = si[a], ib = si[p2];
          const bool aFirst = (va > vb) || (va == vb && ia < ib);
          const bool desc = ((a & k) == 0);
          if (desc ? !aFirst : aFirst) {
            sv[a] = vb; sv[p2] = va;
            si[a] = ib; si[p2] = ia;
          }
        }
      }
      __syncthreads();
    }
  }

  for (int pos = t; pos < NKEEP * DD; pos += 256) {
    const int kk = pos >> 6, d = pos & 63;
    out[((size_t)b * NKEEP + kk) * DD + d] =
        h[((size_t)b * NN + si[kk]) * DD + d] * sv[kk];
  }
}

extern "C" void kernel_launch(void* const* d_in, const int* in_sizes, int n_in,
                              void* d_out, int out_size, void* d_ws, size_t ws_size,
                              hipStream_t stream) {
  const float* x     = (const float*)d_in[0];
  const float* apw   = (const float*)d_in[1];
  const float* apb   = (const float*)d_in[2];
  const float* aw    = (const float*)d_in[3];
  const float* pwa   = (const float*)d_in[4];
  const float* pwab  = (const float*)d_in[5];
  const float* pwoa  = (const float*)d_in[6];
  const float* pwob  = (const float*)d_in[7];
  const float* gam   = (const float*)d_in[8];
  const float* bet   = (const float*)d_in[9];
  const float* mu    = (const float*)d_in[10];
  const float* var   = (const float*)d_in[11];
  const float* poolw = (const float*)d_in[12];
  const float* poolb = (const float*)d_in[13];
  float* out = (float*)d_out;

  float* agg = (float*)d_ws;                  // 131072 f
  float* h   = agg + (size_t)BSZ * NN * DD;   // 131072 f
  float* s   = h + (size_t)BSZ * NN * DD;     // 2048 f
  ushort* wht = (ushort*)(s + BSZ * NN);      // 4096 bf16 (16B aligned)
  ushort* wlt = wht + 4096;                   // 4096 bf16

  k_prep<<<16, 256, 0, stream>>>(apw, wht, wlt);
  k_att2<<<BSZ * NN, 256, 0, stream>>>(x, wht, wlt, apb, aw, agg);
  k_h<<<BSZ * NN / 4, 256, 0, stream>>>(x, agg, pwa, pwab, pwoa, pwob,
                                        gam, bet, mu, var, poolw, poolb, h, s);
  k_topk<<<BSZ, 256, 0, stream>>>(s, h, out);
}

// Round 3
// 82.779 us; speedup vs baseline: 3.4829x; 1.3393x over previous
//
#include <hip/hip_runtime.h>
#include <hip/hip_bf16.h>
#include <math.h>

#define BSZ 4
#define NN 512
#define DD 64
#define NKEEP 256

typedef __attribute__((ext_vector_type(8))) short short8;
typedef __attribute__((ext_vector_type(4))) float f32x4;

__device__ __forceinline__ ushort f2bf_rne(float f) {
  union { float f; unsigned u; } v; v.f = f;
  unsigned r = v.u + 0x7fffu + ((v.u >> 16) & 1u);
  return (ushort)(r >> 16);
}
__device__ __forceinline__ float bf2f(ushort h) {
  union { unsigned u; float f; } v; v.u = ((unsigned)h) << 16;
  return v.f;
}
__device__ __forceinline__ float fast_tanh(float x) {
  float e = __builtin_amdgcn_exp2f(x * 2.8853900817779268f);
  float r = __builtin_amdgcn_rcpf(e + 1.0f);
  return 1.0f - 2.0f * r;
}

// ================= Kernel A: raw scores via Y_e = Xi*diag(w_e) trick =========
// grid 256 = (b:4) x (i-tile16:32) x (j-half256:2); 512 threads (8 waves).
// Wave w owns 32 j. scores[b,i,j] = sum_e aw[e]*tanh( Xj . Y_e + apb[e] ).
__global__ __launch_bounds__(512) void k_score(
    const float* __restrict__ x, const float* __restrict__ apw,
    const float* __restrict__ apb, const float* __restrict__ aw,
    float* __restrict__ sT) {
  __shared__ float Wt[64 * 64];       // Wt[e][d], 16 KB
  __shared__ float Xi[16 * 64];       // Xi[i][d], 4 KB
  __shared__ ushort Y8h[8 * 16 * 64]; // 16 KB, swizzled
  __shared__ ushort Y8l[8 * 16 * 64]; // 16 KB
  __shared__ float apb_s[64], aw_s[64];

  const int t = threadIdx.x;
  const int w = t >> 6, l = t & 63;
  const int bid = blockIdx.x;
  const int b = bid >> 6;
  const int it = (bid & 63) >> 1;
  const int jh = bid & 1;
  const int i0 = it * 16;
  const int j0 = jh * 256;
  const float* xb = x + (size_t)b * NN * DD;

  // ---- stage Wt (transpose of apw[d][e]) ----
  {
    const int d = t >> 3, e0 = (t & 7) * 8;
    float4 v0 = *reinterpret_cast<const float4*>(apw + d * 64 + e0);
    float4 v1 = *reinterpret_cast<const float4*>(apw + d * 64 + e0 + 4);
    Wt[(e0 + 0) * 64 + d] = v0.x; Wt[(e0 + 1) * 64 + d] = v0.y;
    Wt[(e0 + 2) * 64 + d] = v0.z; Wt[(e0 + 3) * 64 + d] = v0.w;
    Wt[(e0 + 4) * 64 + d] = v1.x; Wt[(e0 + 5) * 64 + d] = v1.y;
    Wt[(e0 + 6) * 64 + d] = v1.z; Wt[(e0 + 7) * 64 + d] = v1.w;
  }
  // ---- stage Xi (16 rows x 64 d): one float2 per thread ----
  {
    const int row = t >> 5, dp = (t & 31) * 2;
    float2 v = *reinterpret_cast<const float2*>(xb + (size_t)(i0 + row) * DD + dp);
    Xi[row * 64 + dp] = v.x; Xi[row * 64 + dp + 1] = v.y;
  }
  if (t < 64) { apb_s[t] = apb[t]; aw_s[t] = aw[t]; }

  // ---- A-frags (Xj) direct from global, split hi/lo, e-independent ----
  short8 ah[2][2], al[2][2];
  {
    const int g = l >> 4;
    #pragma unroll
    for (int jq = 0; jq < 2; ++jq) {
      const int j = j0 + w * 32 + jq * 16 + (l & 15);
      #pragma unroll
      for (int ks = 0; ks < 2; ++ks) {
        const float* xr = xb + (size_t)j * DD + ks * 32 + g * 8;
        float4 u0 = *reinterpret_cast<const float4*>(xr);
        float4 u1 = *reinterpret_cast<const float4*>(xr + 4);
        float vv[8] = {u0.x, u0.y, u0.z, u0.w, u1.x, u1.y, u1.z, u1.w};
        short8 hh, ll;
        #pragma unroll
        for (int q = 0; q < 8; ++q) {
          ushort hq = f2bf_rne(vv[q]);
          hh[q] = (short)hq;
          ll[q] = (short)f2bf_rne(vv[q] - bf2f(hq));
        }
        ah[jq][ks] = hh; al[jq][ks] = ll;
      }
    }
  }

  const int yi = t >> 5;          // Y-build: i row 0..15
  const int ydp = (t & 31) * 2;   // Y-build: d pair base
  f32x4 srews[2];
  srews[0] = (f32x4){0.f, 0.f, 0.f, 0.f};
  srews[1] = (f32x4){0.f, 0.f, 0.f, 0.f};

  __syncthreads();  // staging visible
  const float xi0 = Xi[yi * 64 + ydp], xi1 = Xi[yi * 64 + ydp + 1];

  #pragma unroll 1
  for (int r = 0; r < 8; ++r) {
    // ---- coop-build Y8 for e = r*8 .. r*8+7 (split hi/lo, swizzled) ----
    #pragma unroll
    for (int p = 0; p < 8; ++p) {
      const int e = r * 8 + p;
      const float v0 = xi0 * Wt[e * 64 + ydp];
      const float v1 = xi1 * Wt[e * 64 + ydp + 1];
      const ushort h0 = f2bf_rne(v0), h1 = f2bf_rne(v1);
      const ushort l0v = f2bf_rne(v0 - bf2f(h0)), l1v = f2bf_rne(v1 - bf2f(h1));
      const int byteoff = (p * 2048 + yi * 128 + ydp * 2) ^ ((yi & 7) << 4);
      *reinterpret_cast<uint*>(reinterpret_cast<char*>(Y8h) + byteoff) =
          (uint)h0 | ((uint)h1 << 16);
      *reinterpret_cast<uint*>(reinterpret_cast<char*>(Y8l) + byteoff) =
          (uint)l0v | ((uint)l1v << 16);
    }
    __syncthreads();  // Y8 published

    for (int p = 0; p < 8; ++p) {
      const int e = r * 8 + p;
      const int il = l & 15, g = l >> 4;
      short8 bh[2], bl[2];
      #pragma unroll
      for (int ks = 0; ks < 2; ++ks) {
        const int byteoff =
            (p * 2048 + (il * 64 + ks * 32 + g * 8) * 2) ^ ((il & 7) << 4);
        bh[ks] = *reinterpret_cast<const short8*>(
            reinterpret_cast<const char*>(Y8h) + byteoff);
        bl[ks] = *reinterpret_cast<const short8*>(
            reinterpret_cast<const char*>(Y8l) + byteoff);
      }
      f32x4 acc[2];
      acc[0] = (f32x4){0.f, 0.f, 0.f, 0.f};
      acc[1] = (f32x4){0.f, 0.f, 0.f, 0.f};
      #pragma unroll
      for (int jq = 0; jq < 2; ++jq)
        #pragma unroll
        for (int ks = 0; ks < 2; ++ks) {
          acc[jq] = __builtin_amdgcn_mfma_f32_16x16x32_bf16(ah[jq][ks], bh[ks], acc[jq], 0, 0, 0);
          acc[jq] = __builtin_amdgcn_mfma_f32_16x16x32_bf16(ah[jq][ks], bl[ks], acc[jq], 0, 0, 0);
          acc[jq] = __builtin_amdgcn_mfma_f32_16x16x32_bf16(al[jq][ks], bh[ks], acc[jq], 0, 0, 0);
        }
      const float bias = apb_s[e], awv = aw_s[e];
      #pragma unroll
      for (int jq = 0; jq < 2; ++jq)
        #pragma unroll
        for (int rr = 0; rr < 4; ++rr)
          srews[jq][rr] += awv * fast_tanh(acc[jq][rr] + bias);
    }
    __syncthreads();  // Y8 consumed
  }

  // ---- store raw scores transposed: sT[b][j][i] ----
  const int iouter = i0 + (l & 15);
  #pragma unroll
  for (int jq = 0; jq < 2; ++jq)
    #pragma unroll
    for (int rr = 0; rr < 4; ++rr) {
      const int j = j0 + w * 32 + jq * 16 + (l >> 4) * 4 + rr;
      sT[(size_t)b * NN * NN + (size_t)j * NN + iouter] = srews[jq][rr];
    }
}

// ====== Kernel B: per (b,i): softmax + agg + h(BN,SELU) + pool score s =======
__global__ __launch_bounds__(256) void k_soft(
    const float* __restrict__ x, const float* __restrict__ sT,
    const float* __restrict__ pwa, const float* __restrict__ pwab,
    const float* __restrict__ pwoa, const float* __restrict__ pwob,
    const float* __restrict__ gam, const float* __restrict__ bet,
    const float* __restrict__ mu, const float* __restrict__ var,
    const float* __restrict__ poolw, const float* __restrict__ poolb,
    float* __restrict__ h, float* __restrict__ s) {
  __shared__ float ssc[NN];
  __shared__ float sred[8];
  __shared__ float sagg[4][DD];
  __shared__ float sxi[DD];
  __shared__ float ragg[DD];
  __shared__ float spool[4];

  const int t = threadIdx.x;
  const int w = t >> 6, l = t & 63;
  const int b = blockIdx.x >> 9;
  const int i = blockIdx.x & (NN - 1);
  const float* xb = x + (size_t)b * NN * DD;

  if (t < 64) sxi[t] = xb[(size_t)i * DD + t];

  float sc0 = sT[(size_t)b * NN * NN + (size_t)t * NN + i];
  float sc1 = sT[(size_t)b * NN * NN + (size_t)(t + 256) * NN + i];

  float m = fmaxf(sc0, sc1);
  #pragma unroll
  for (int off = 32; off; off >>= 1) m = fmaxf(m, __shfl_xor(m, off, 64));
  if (l == 0) sred[w] = m;
  __syncthreads();
  m = fmaxf(fmaxf(sred[0], sred[1]), fmaxf(sred[2], sred[3]));

  const float L2E = 1.4426950408889634f;
  float e0 = __builtin_amdgcn_exp2f((sc0 - m) * L2E);
  float e1 = __builtin_amdgcn_exp2f((sc1 - m) * L2E);
  float ps = e0 + e1;
  #pragma unroll
  for (int off = 32; off; off >>= 1) ps += __shfl_xor(ps, off, 64);
  if (l == 0) sred[4 + w] = ps;
  __syncthreads();
  const float S = sred[4] + sred[5] + sred[6] + sred[7];
  const float inv = 1.f / S;
  ssc[t] = e0 * inv;
  ssc[t + 256] = e1 * inv;
  __syncthreads();

  // agg[b,i,d] = sum_j att[j]*x[b,j,d]
  const int c2 = t >> 6, d = t & 63;
  float part = 0.f;
  #pragma unroll 4
  for (int q = 0; q < 128; ++q) {
    const int j = c2 * 128 + q;
    part = fmaf(ssc[j], xb[(size_t)j * DD + d], part);
  }
  sagg[c2][d] = part;
  __syncthreads();
  if (t < 64) ragg[t] = sagg[0][t] + sagg[1][t] + sagg[2][t] + sagg[3][t];
  __syncthreads();

  // h[e] = agg.pwa[:,e] + xi.pwoa[:,e] + biases; BN; SELU
  const int e = w * 16 + (l & 15), dg = l >> 4;
  float acc = 0.f;
  #pragma unroll
  for (int q = 0; q < 16; ++q) {
    const int dd2 = dg * 16 + q;
    acc = fmaf(ragg[dd2], pwa[dd2 * 64 + e], acc);
    acc = fmaf(sxi[dd2], pwoa[dd2 * 64 + e], acc);
  }
  acc += __shfl_xor(acc, 16, 64);
  acc += __shfl_xor(acc, 32, 64);
  acc += pwab[e] + pwob[e];
  float hb = (acc - mu[e]) * rsqrtf(var[e] + 1e-5f) * gam[e] + bet[e];
  const float SC = 1.0507009873554805f, AL = 1.6732632423543772f;
  float hv = hb > 0.f ? SC * hb : SC * AL * expm1f(hb);
  if (dg == 0) h[((size_t)(b * NN + i)) * DD + e] = hv;

  float p = hv * poolw[e];
  p += __shfl_xor(p, 1, 64);
  p += __shfl_xor(p, 2, 64);
  p += __shfl_xor(p, 4, 64);
  p += __shfl_xor(p, 8, 64);
  if (l == 0) spool[w] = p;
  __syncthreads();
  if (t == 0) {
    float tot = spool[0] + spool[1] + spool[2] + spool[3] + poolb[0];
    s[b * NN + i] = 1.f / (1.f + expf(-tot));
  }
}

// ---------------- Kernel C: per-batch top-k (bitonic sort) + gather ----------
__global__ __launch_bounds__(256) void k_topk(
    const float* __restrict__ s, const float* __restrict__ h,
    float* __restrict__ out) {
  __shared__ float sv[NN];
  __shared__ int si[NN];
  const int b = blockIdx.x, t = threadIdx.x;
  sv[t] = s[b * NN + t];
  sv[t + 256] = s[b * NN + t + 256];
  si[t] = t;
  si[t + 256] = t + 256;
  __syncthreads();

  for (int k = 2; k <= NN; k <<= 1) {
    for (int j = k >> 1; j > 0; j >>= 1) {
      #pragma unroll
      for (int base = 0; base < 2; ++base) {
        const int a = t + base * 256;
        const int p2 = a ^ j;
        if (p2 > a) {
          float va = sv[a], vb = sv[p2];
          int ia = si[a], ib = si[p2];
          const bool aFirst = (va > vb) || (va == vb && ia < ib);
          const bool desc = ((a & k) == 0);
          if (desc ? !aFirst : aFirst) {
            sv[a] = vb; sv[p2] = va;
            si[a] = ib; si[p2] = ia;
          }
        }
      }
      __syncthreads();
    }
  }

  for (int pos = t; pos < NKEEP * DD; pos += 256) {
    const int kk = pos >> 6, d = pos & 63;
    out[((size_t)b * NKEEP + kk) * DD + d] =
        h[((size_t)b * NN + si[kk]) * DD + d] * sv[kk];
  }
}

extern "C" void kernel_launch(void* const* d_in, const int* in_sizes, int n_in,
                              void* d_out, int out_size, void* d_ws, size_t ws_size,
                              hipStream_t stream) {
  const float* x     = (const float*)d_in[0];
  const float* apw   = (const float*)d_in[1];
  const float* apb   = (const float*)d_in[2];
  const float* aw    = (const float*)d_in[3];
  const float* pwa   = (const float*)d_in[4];
  const float* pwab  = (const float*)d_in[5];
  const float* pwoa  = (const float*)d_in[6];
  const float* pwob  = (const float*)d_in[7];
  const float* gam   = (const float*)d_in[8];
  const float* bet   = (const float*)d_in[9];
  const float* mu    = (const float*)d_in[10];
  const float* var   = (const float*)d_in[11];
  const float* poolw = (const float*)d_in[12];
  const float* poolb = (const float*)d_in[13];
  float* out = (float*)d_out;

  float* sT = (float*)d_ws;                        // 4*512*512 f = 4 MB
  float* h  = sT + (size_t)BSZ * NN * NN;          // 131072 f
  float* s  = h + (size_t)BSZ * NN * DD;           // 2048 f

  k_score<<<256, 512, 0, stream>>>(x, apw, apb, aw, sT);
  k_soft<<<BSZ * NN, 256, 0, stream>>>(x, sT, pwa, pwab, pwoa, pwob,
                                       gam, bet, mu, var, poolw, poolb, h, s);
  k_topk<<<BSZ, 256, 0, stream>>>(s, h, out);
}